// Round 1
// baseline (390.446 us; speedup 1.0000x reference)
//
#include <hip/hip_runtime.h>
#include <hip/hip_bf16.h>

#define BS 4
#define SEQ 2048
#define DIM 512
#define HEADS 8
#define HD 64
#define ROWS (BS*SEQ)   // 8192
#define NEGV -1000000.0f

typedef __attribute__((ext_vector_type(8))) short bf16x8;
typedef __attribute__((ext_vector_type(4))) float floatx4;

__device__ __forceinline__ unsigned short f2bf(float f) {
    union { float f; unsigned u; } v; v.f = f;
    unsigned r = v.u + 0x7fff + ((v.u >> 16) & 1);
    return (unsigned short)(r >> 16);
}

// ---------------- fp32 -> bf16 conversion of x and the 4 weight matrices ----
// 4 elems per thread. x: 1048576 units, each W: 65536 units. grid = 5120*256.
__global__ __launch_bounds__(256) void convert_all(
    const float* __restrict__ x, const float* __restrict__ Wq,
    const float* __restrict__ Wk, const float* __restrict__ Wv,
    const float* __restrict__ Wo,
    unsigned short* __restrict__ xb, unsigned short* __restrict__ wqb,
    unsigned short* __restrict__ wkb, unsigned short* __restrict__ wvb,
    unsigned short* __restrict__ wob)
{
    int i = blockIdx.x * 256 + threadIdx.x;
    const float* src; unsigned short* dst; int off;
    if (i < 1048576) { src = x; dst = xb; off = i; }
    else {
        int j = i - 1048576; int seg = j >> 16; off = j & 65535;
        src = seg == 0 ? Wq : seg == 1 ? Wk : seg == 2 ? Wv : Wo;
        dst = seg == 0 ? wqb : seg == 1 ? wkb : seg == 2 ? wvb : wob;
    }
    float4 v = ((const float4*)src)[off];
    ushort4 o;
    o.x = f2bf(v.x); o.y = f2bf(v.y); o.z = f2bf(v.z); o.w = f2bf(v.w);
    ((ushort4*)dst)[off] = o;
}

// ---------------- QKV projection: C = A @ W^T, head-split bf16 output -------
// A: ROWS x DIM bf16, W: DIM x DIM bf16 (row j = column j of W^T -> BT form).
// Block: 256 thr = 4 waves, tile 64(M) x 64(N); wave w does rows w*16..+15.
// grid: (DIM/64, ROWS/64, 3), z picks (W, Out).
__global__ __launch_bounds__(256) void gemm_qkv(
    const unsigned short* __restrict__ A,
    const unsigned short* __restrict__ W0, const unsigned short* __restrict__ W1,
    const unsigned short* __restrict__ W2,
    unsigned short* __restrict__ O0, unsigned short* __restrict__ O1,
    unsigned short* __restrict__ O2)
{
    const unsigned short* Bt = blockIdx.z == 0 ? W0 : blockIdx.z == 1 ? W1 : W2;
    unsigned short* Out      = blockIdx.z == 0 ? O0 : blockIdx.z == 1 ? O1 : O2;
    int n0 = blockIdx.x * 64;
    int m0 = blockIdx.y * 64;
    int tid = threadIdx.x;
    int w = tid >> 6, lane = tid & 63, quad = lane >> 4, l16 = lane & 15;

    const unsigned short* Ap = A + (long)(m0 + w*16 + l16) * DIM + quad * 8;
    const unsigned short* Bp = Bt + (long)(n0 + l16) * DIM + quad * 8;

    floatx4 acc[4];
    #pragma unroll
    for (int ct = 0; ct < 4; ct++) acc[ct] = (floatx4){0.f, 0.f, 0.f, 0.f};

    for (int k0 = 0; k0 < DIM; k0 += 32) {
        bf16x8 a = *(const bf16x8*)(Ap + k0);
        #pragma unroll
        for (int ct = 0; ct < 4; ct++) {
            bf16x8 b = *(const bf16x8*)(Bp + (long)ct * 16 * DIM + k0);
            acc[ct] = __builtin_amdgcn_mfma_f32_16x16x32_bf16(a, b, acc[ct], 0, 0, 0);
        }
    }
    // C layout: col = l16, row = quad*4 + r  (verified m89/m91)
    #pragma unroll
    for (int ct = 0; ct < 4; ct++) {
        #pragma unroll
        for (int r = 0; r < 4; r++) {
            int row = m0 + w*16 + quad*4 + r;       // global (b*SEQ + n)
            int col = n0 + ct*16 + l16;             // global (h*HD + d)
            int b = row >> 11, n = row & 2047, h = col >> 6, d = col & 63;
            Out[(((long)(b * HEADS + h) * SEQ + n) << 6) + d] = f2bf(acc[ct][r]);
        }
    }
}

// ---------------- flash attention -------------------------------------------
// Block: (b, h, 64 query rows), 4 waves x 16 rows. Key tiles of 64.
__global__ __launch_bounds__(256) void flash_attn(
    const unsigned short* __restrict__ Q, const unsigned short* __restrict__ K,
    const unsigned short* __restrict__ V, const int* __restrict__ mask,
    unsigned short* __restrict__ ctx)
{
    __shared__ unsigned short Kt[64 * 72];      // [key][dim], padded stride 72
    __shared__ unsigned short Vt[64 * 72];      // [dim][key], padded stride 72
    __shared__ unsigned short Pt[4][16 * 72];   // per-wave P tile [row][key]
    __shared__ float keepf[64];

    int bx = blockIdx.x;
    int q0 = (bx & 31) * 64;
    int h  = (bx >> 5) & 7;
    int b  = bx >> 8;
    long bh = (long)(b * HEADS + h) * SEQ;

    int tid = threadIdx.x;
    int w = tid >> 6, lane = tid & 63, quad = lane >> 4, l16 = lane & 15;

    // Q fragments (A-operand layout: m=l16, k=quad*8+j), kept in regs
    const unsigned short* Qp = Q + (bh + q0 + w*16 + l16) * HD + quad * 8;
    bf16x8 qa0 = *(const bf16x8*)(Qp);
    bf16x8 qa1 = *(const bf16x8*)(Qp + 32);

    floatx4 o[4];
    float m_i[4], l_i[4];
    #pragma unroll
    for (int ct = 0; ct < 4; ct++) o[ct] = (floatx4){0.f, 0.f, 0.f, 0.f};
    #pragma unroll
    for (int r = 0; r < 4; r++) { m_i[r] = -1e30f; l_i[r] = 0.f; }

    int skey = tid >> 3;            // 0..31
    int sdim = (tid & 7) * 8;       // 0,8,..,56

    for (int kt = 0; kt < SEQ; kt += 64) {
        __syncthreads();
        // ---- stage K tile (row-major) and V tile (transposed) into LDS ----
        #pragma unroll
        for (int it = 0; it < 2; it++) {
            int key = skey + it * 32;
            uint4 kv = *(const uint4*)(K + (bh + kt + key) * HD + sdim);
            *(uint4*)&Kt[key * 72 + sdim] = kv;
            union { uint4 q; unsigned short s[8]; } uv;
            uv.q = *(const uint4*)(V + (bh + kt + key) * HD + sdim);
            #pragma unroll
            for (int i2 = 0; i2 < 8; i2++)
                Vt[(sdim + i2) * 72 + key] = uv.s[i2];
        }
        if (tid < 64)
            keepf[tid] = (mask[b * SEQ + kt + tid] == 1) ? 1.0f : 0.0f;
        __syncthreads();

        // ---- scores S = Q.K^T / 8, mask -> exact -1e6 (matches where) ----
        float sc[4][4];
        #pragma unroll
        for (int nt = 0; nt < 4; nt++) {
            const unsigned short* kb = &Kt[(nt * 16 + l16) * 72 + quad * 8];
            bf16x8 kb0 = *(const bf16x8*)(kb);
            bf16x8 kb1 = *(const bf16x8*)(kb + 32);
            floatx4 s = (floatx4){0.f, 0.f, 0.f, 0.f};
            s = __builtin_amdgcn_mfma_f32_16x16x32_bf16(qa0, kb0, s, 0, 0, 0);
            s = __builtin_amdgcn_mfma_f32_16x16x32_bf16(qa1, kb1, s, 0, 0, 0);
            float kp = keepf[nt * 16 + l16];
            #pragma unroll
            for (int r = 0; r < 4; r++)
                sc[nt][r] = (kp != 0.f) ? s[r] * 0.125f : NEGV;
        }

        // ---- online softmax (row stats live on all 16 lanes of the group) --
        float mnew[4], alpha[4], rsum[4];
        #pragma unroll
        for (int r = 0; r < 4; r++) {
            float v = fmaxf(fmaxf(sc[0][r], sc[1][r]), fmaxf(sc[2][r], sc[3][r]));
            #pragma unroll
            for (int off = 1; off < 16; off <<= 1)
                v = fmaxf(v, __shfl_xor(v, off));
            mnew[r] = fmaxf(m_i[r], v);
            alpha[r] = __expf(m_i[r] - mnew[r]);
            m_i[r] = mnew[r];
        }
        #pragma unroll
        for (int r = 0; r < 4; r++) {
            float s = 0.f;
            #pragma unroll
            for (int nt = 0; nt < 4; nt++) {
                float p = __expf(sc[nt][r] - mnew[r]);
                s += p;
                Pt[w][(quad * 4 + r) * 72 + nt * 16 + l16] = f2bf(p);
            }
            #pragma unroll
            for (int off = 1; off < 16; off <<= 1)
                s += __shfl_xor(s, off);
            l_i[r] = l_i[r] * alpha[r] + s;
        }
        #pragma unroll
        for (int ct = 0; ct < 4; ct++)
            #pragma unroll
            for (int r = 0; r < 4; r++)
                o[ct][r] *= alpha[r];

        // ---- P (A-layout via LDS round-trip) @ V ----
        bf16x8 pa0 = *(const bf16x8*)&Pt[w][l16 * 72 + quad * 8];
        bf16x8 pa1 = *(const bf16x8*)&Pt[w][l16 * 72 + 32 + quad * 8];
        #pragma unroll
        for (int ct = 0; ct < 4; ct++) {
            const unsigned short* vb = &Vt[(ct * 16 + l16) * 72 + quad * 8];
            bf16x8 vb0 = *(const bf16x8*)(vb);
            bf16x8 vb1 = *(const bf16x8*)(vb + 32);
            o[ct] = __builtin_amdgcn_mfma_f32_16x16x32_bf16(pa0, vb0, o[ct], 0, 0, 0);
            o[ct] = __builtin_amdgcn_mfma_f32_16x16x32_bf16(pa1, vb1, o[ct], 0, 0, 0);
        }
    }

    // ---- epilogue: ctx[b*SEQ+q][h*64 + d] = O / l ----
    float inv[4];
    #pragma unroll
    for (int r = 0; r < 4; r++) inv[r] = 1.0f / l_i[r];
    #pragma unroll
    for (int ct = 0; ct < 4; ct++) {
        #pragma unroll
        for (int r = 0; r < 4; r++) {
            int row = q0 + w*16 + quad*4 + r;
            int col = h * HD + ct * 16 + l16;
            ctx[(long)(b * SEQ + row) * DIM + col] = f2bf(o[ct][r] * inv[r]);
        }
    }
}

// ---------------- output projection: out = ctx @ Wo^T (fp32 out) ------------
__global__ __launch_bounds__(256) void gemm_proj(
    const unsigned short* __restrict__ A, const unsigned short* __restrict__ Bt,
    float* __restrict__ Out)
{
    int n0 = blockIdx.x * 64;
    int m0 = blockIdx.y * 64;
    int tid = threadIdx.x;
    int w = tid >> 6, lane = tid & 63, quad = lane >> 4, l16 = lane & 15;

    const unsigned short* Ap = A + (long)(m0 + w*16 + l16) * DIM + quad * 8;
    const unsigned short* Bp = Bt + (long)(n0 + l16) * DIM + quad * 8;

    floatx4 acc[4];
    #pragma unroll
    for (int ct = 0; ct < 4; ct++) acc[ct] = (floatx4){0.f, 0.f, 0.f, 0.f};

    for (int k0 = 0; k0 < DIM; k0 += 32) {
        bf16x8 a = *(const bf16x8*)(Ap + k0);
        #pragma unroll
        for (int ct = 0; ct < 4; ct++) {
            bf16x8 b = *(const bf16x8*)(Bp + (long)ct * 16 * DIM + k0);
            acc[ct] = __builtin_amdgcn_mfma_f32_16x16x32_bf16(a, b, acc[ct], 0, 0, 0);
        }
    }
    #pragma unroll
    for (int ct = 0; ct < 4; ct++) {
        #pragma unroll
        for (int r = 0; r < 4; r++) {
            int row = m0 + w*16 + quad*4 + r;
            int col = n0 + ct*16 + l16;
            Out[(long)row * DIM + col] = acc[ct][r];
        }
    }
}

extern "C" void kernel_launch(void* const* d_in, const int* in_sizes, int n_in,
                              void* d_out, int out_size, void* d_ws, size_t ws_size,
                              hipStream_t stream) {
    const float* x  = (const float*)d_in[0];
    const float* Wq = (const float*)d_in[1];
    const float* Wk = (const float*)d_in[2];
    const float* Wv = (const float*)d_in[3];
    const float* Wo = (const float*)d_in[4];
    const int* mask = (const int*)d_in[5];
    float* out = (float*)d_out;

    char* ws = (char*)d_ws;
    size_t off = 0;
    unsigned short* xb  = (unsigned short*)(ws + off); off += (size_t)ROWS * DIM * 2;
    unsigned short* wqb = (unsigned short*)(ws + off); off += (size_t)DIM * DIM * 2;
    unsigned short* wkb = (unsigned short*)(ws + off); off += (size_t)DIM * DIM * 2;
    unsigned short* wvb = (unsigned short*)(ws + off); off += (size_t)DIM * DIM * 2;
    unsigned short* wob = (unsigned short*)(ws + off); off += (size_t)DIM * DIM * 2;
    unsigned short* Qh  = (unsigned short*)(ws + off); off += (size_t)ROWS * HD * HEADS / HEADS * 2 * HEADS / HEADS; // ROWS*HD*... (see below)
    // Qh/Kh/Vh are (B,H,SEQ,HD) = ROWS*HD per head-group... full size = BS*HEADS*SEQ*HD = ROWS*DIM/HD*HD = 4194304 elems
    off = ((size_t)ROWS * DIM + 4 * (size_t)DIM * DIM) * 2; // rewind to after weights
    Qh = (unsigned short*)(ws + off); off += (size_t)BS * HEADS * SEQ * HD * 2;
    unsigned short* Kh  = (unsigned short*)(ws + off); off += (size_t)BS * HEADS * SEQ * HD * 2;
    unsigned short* Vh  = (unsigned short*)(ws + off); off += (size_t)BS * HEADS * SEQ * HD * 2;
    unsigned short* ctx = (unsigned short*)(ws + off); off += (size_t)ROWS * DIM * 2;

    convert_all<<<5120, 256, 0, stream>>>(x, Wq, Wk, Wv, Wo, xb, wqb, wkb, wvb, wob);
    gemm_qkv<<<dim3(DIM / 64, ROWS / 64, 3), 256, 0, stream>>>(xb, wqb, wkb, wvb, Qh, Kh, Vh);
    flash_attn<<<BS * HEADS * (SEQ / 64), 256, 0, stream>>>(Qh, Kh, Vh, mask, ctx);
    gemm_proj<<<dim3(DIM / 64, ROWS / 64), 256, 0, stream>>>(ctx, wob, out);

    (void)in_sizes; (void)n_in; (void)out_size; (void)ws_size;
}